// Round 4
// baseline (399.927 us; speedup 1.0000x reference)
//
#include <hip/hip_runtime.h>
#include <cstdint>
#include <cstddef>

// Problem constants (from reference)
#define BB      512
#define CC      256
#define KXX     6
#define KZZ     22
#define HO      17                 // 22 - 6 + 1
#define OUTHW   (HO * HO)          // 289
#define ZCH     (KZZ * KZZ)        // 484 floats per (b,c) of z
#define XCH     (KXX * KXX)        // 36 floats per (b,c) of x

// Tiling: one block per sample, 512 blocks = 2/CU. Triple-buffered chunk
// pipeline with manual vmcnt so the steady state NEVER drains the DMA
// queue to zero (the __syncthreads vmcnt(0) drain cost ~1000-1500 cyc/chunk).
#define CHUNK_C   8                          // channels staged per chunk
#define NCHUNK    (CC / CHUNK_C)             // 32
#define ZCHUNK    (CHUNK_C * ZCH)            // 3872 floats = 15488 B
#define XCHUNK    (CHUNK_C * XCH)            // 288 floats  = 1152 B
#define NBUF      3
#define NT        320                        // 5 waves

typedef const __attribute__((address_space(1))) void* gptr_t;
typedef __attribute__((address_space(3))) void* lptr_t;

__device__ __forceinline__ void cp16_async(void* lds_base, const void* gsrc) {
  __builtin_amdgcn_global_load_lds((gptr_t)gsrc, (lptr_t)lds_base, 16, 0, 0);
}
__device__ __forceinline__ void cp4_async(void* lds_base, const void* gsrc) {
  __builtin_amdgcn_global_load_lds((gptr_t)gsrc, (lptr_t)lds_base, 4, 0, 0);
}

// Stage one chunk with EXACTLY 4 VMEM instructions per wave (vmcnt(4) at the
// next pipeline stage then waits for precisely this chunk's loads):
//  wave0: 3x z cp16 + z-tail cp4
//  wave1: 3x z cp16 + x cp16
//  wave2: 3x z cp16 + x-tail cp4
//  wave3: 3x z cp16 + dummy cp4 (scratch)
//  wave4: 3x z cp16 + dummy cp4 (scratch)
__device__ __forceinline__ void stage_chunk(float* zdst, float* xdst,
                                            float* scratch,
                                            const float* zsrc, const float* xsrc,
                                            int wave, int lane) {
  char* zd = (char*)zdst;
  const char* zs = (const char*)zsrc;
#pragma unroll
  for (int i = 0; i < 3; ++i) {               // 15 full 1 KiB groups, 3 per wave
    const int grp = wave * 3 + i;
    cp16_async(zd + grp * 1024, zs + grp * 1024 + lane * 16);
  }
  if (wave == 0) {
    if (lane < 32) cp4_async(zd + 15360, zs + 15360 + lane * 4);   // z tail 128 B
  } else if (wave == 1) {
    cp16_async((char*)xdst, (const char*)xsrc + lane * 16);        // x 1024 B
  } else if (wave == 2) {
    if (lane < 32) cp4_async((char*)xdst + 1024, (const char*)xsrc + 1024 + lane * 4);
  } else {
    // dummy: keeps per-wave VMEM count uniform; result never read
    if (lane < 32) cp4_async((char*)scratch, zs + lane * 4);
  }
}

__device__ __forceinline__ void pipe_barrier() {
  asm volatile("" ::: "memory");
  __builtin_amdgcn_s_barrier();
  asm volatile("" ::: "memory");
}

__global__ __launch_bounds__(NT, 2) void corr_kernel(const float* __restrict__ x,
                                                     const float* __restrict__ z,
                                                     float* __restrict__ out) {
  // 3*(15488+1152) + 128 = 50048 B LDS -> 2 blocks/CU (100 KB of 160 KB)
  __shared__ __align__(16) float zbuf[NBUF][ZCHUNK];
  __shared__ __align__(16) float xbuf[NBUF][XCHUNK];
  __shared__ __align__(16) float scratch[32];

  const int b    = blockIdx.x;
  const int t    = threadIdx.x;
  const int wave = t >> 6;
  const int lane = t & 63;

  const float* zb = z + (size_t)b * (CC * ZCH);
  const float* xb = x + (size_t)b * (CC * XCH);

  // Prime the pipeline: chunks 0 and 1 in flight (8 VMEM ops/wave).
  stage_chunk(zbuf[0], xbuf[0], scratch, zb, xb, wave, lane);
  stage_chunk(zbuf[1], xbuf[1], scratch, zb + ZCHUNK, xb + XCHUNK, wave, lane);

  // Compute mapping: 272 active threads = 16 groups x 17 output rows.
  const int  g      = t / 17;
  const int  oy     = t - g * 17;
  const int  cl     = g & 7;
  const int  kyh    = g >> 3;           // 0: ky 0..2, 1: ky 3..5
  const bool active = (g < 16);

  float acc[HO];
#pragma unroll
  for (int i = 0; i < HO; ++i) acc[i] = 0.0f;

  for (int k = 0; k < NCHUNK; ++k) {
    // Wait for chunk k's DMA (the 4 newest ops per wave are chunk k+1's;
    // everything older — chunk k — must be complete). In-order vmcnt
    // semantics make vmcnt(4) exactly "all but the newest 4 done".
    if (k < NCHUNK - 1) {
      asm volatile("s_waitcnt vmcnt(4)" ::: "memory");
    } else {
      asm volatile("s_waitcnt vmcnt(0)" ::: "memory");
    }
    pipe_barrier();   // all waves' chunk-k loads visible; compute k-1 done everywhere

    // Prefetch chunk k+2 into buf (k+2)%3 (last read finished in iter k-1).
    if (k + 2 < NCHUNK) {
      const int nb = (k + 2) % NBUF;
      stage_chunk(zbuf[nb], xbuf[nb], scratch,
                  zb + (size_t)(k + 2) * ZCHUNK, xb + (size_t)(k + 2) * XCHUNK,
                  wave, lane);
    }

    if (active) {
      const int buf = k % NBUF;
      const float* zc = &zbuf[buf][cl * ZCH];
      const float* xc = &xbuf[buf][cl * XCH + kyh * (3 * KXX)];

      __align__(16) float xv[3 * KXX];
#pragma unroll
      for (int i = 0; i < 9; ++i)
        ((float2*)xv)[i] = ((const float2*)xc)[i];

#pragma unroll
      for (int ky2 = 0; ky2 < 3; ++ky2) {
        const int row = oy + kyh * 3 + ky2;
        const float* zr = zc + row * KZZ;
        __align__(16) float zv[KZZ + 2];
#pragma unroll
        for (int i = 0; i < 11; ++i)
          ((float2*)zv)[i] = ((const float2*)zr)[i]; // 11 ds_read_b64
#pragma unroll
        for (int kx = 0; kx < KXX; ++kx) {
          const float xs = xv[ky2 * KXX + kx];
#pragma unroll
          for (int ox = 0; ox < HO; ++ox)
            acc[ox] = fmaf(zv[ox + kx], xs, acc[ox]); // 17-wide register reuse
        }
      }
    }
  }

  // Cross-group reduction: 16 partials per output. Reuse zbuf[0..1] as
  // scratch (16*289 = 4624 floats <= 7744 in two buffers). No DMA pending.
  __syncthreads();
  float* red = &zbuf[0][0];
  if (active) {
#pragma unroll
    for (int ox = 0; ox < HO; ++ox)
      red[g * OUTHW + oy * HO + ox] = acc[ox];
  }
  __syncthreads();
  if (t < OUTHW) {
    float s = 0.0f;
#pragma unroll
    for (int gg = 0; gg < 16; ++gg) s += red[gg * OUTHW + t];
    out[(size_t)b * OUTHW + t] = s;   // coalesced direct store, no atomics
  }
}

extern "C" void kernel_launch(void* const* d_in, const int* in_sizes, int n_in,
                              void* d_out, int out_size, void* d_ws, size_t ws_size,
                              hipStream_t stream) {
  const float* x = (const float*)d_in[0];   // [512,256,6,6]
  const float* z = (const float*)d_in[1];   // [512,256,22,22]
  float* out = (float*)d_out;               // [512,1,17,17]
  corr_kernel<<<BB, NT, 0, stream>>>(x, z, out);
}

// Round 5
// 381.926 us; speedup vs baseline: 1.0471x; 1.0471x over previous
//
#include <hip/hip_runtime.h>
#include <cstdint>
#include <cstddef>

// Problem constants (from reference)
#define BB      512
#define CC      256
#define KXX     6
#define KZZ     22
#define HO      17                 // 22 - 6 + 1
#define OUTHW   (HO * HO)          // 289
#define ZCH     (KZZ * KZZ)        // 484 floats per (b,c) of z
#define XCH     (KXX * KXX)        // 36 floats per (b,c) of x

// 16-channel super-chunks, double-buffered z in LDS (2 x 30976 B = 61.9 KB,
// under the 64 KB workgroup cap -> 2 blocks/CU). x is loaded to registers
// straight from global (L1-resident) to free LDS.
// Compute mapping: 288 threads = 16 ch x 2 kyh x 9 oy-groups; each thread
// computes TWO output rows -> 4 z-row reads per 2 rows (was 3 per 1),
// cutting LDS read traffic ~1.5x (R4 was LDS-pipe-bound: 1.6e7 conflict
// cycles + 210 ds_read_b64/chunk/block).
#define CHUNK_C   16
#define NCHUNK    (CC / CHUNK_C)             // 16
#define ZCHUNK    (CHUNK_C * ZCH)            // 7744 floats = 30976 B
#define NT        320                        // 5 waves

typedef const __attribute__((address_space(1))) void* gptr_t;
typedef __attribute__((address_space(3))) void* lptr_t;

__device__ __forceinline__ void cp16_async(void* lds_base, const void* gsrc) {
  __builtin_amdgcn_global_load_lds((gptr_t)gsrc, (lptr_t)lds_base, 16, 0, 0);
}

// Stage one 16-channel z super-chunk: 30976 B = 30 x 1024 B + 256 B tail.
// Waves 0..4 take 6 full 1 KiB groups each; wave 0 lanes 0..15 take the tail.
__device__ __forceinline__ void stage_chunk(float* zdst, const float* zsrc,
                                            int wave, int lane) {
  char* zd = (char*)zdst;
  const char* zs = (const char*)zsrc;
#pragma unroll
  for (int i = 0; i < 6; ++i) {
    const int grp = wave * 6 + i;
    cp16_async(zd + grp * 1024, zs + grp * 1024 + lane * 16);
  }
  if (wave == 0 && lane < 16)
    cp16_async(zd + 30720, zs + 30720 + lane * 16);
}

__global__ __launch_bounds__(NT, 2) void corr_kernel(const float* __restrict__ x,
                                                     const float* __restrict__ z,
                                                     float* __restrict__ out) {
  __shared__ __align__(16) float zbuf[2][ZCHUNK];   // 61952 B

  const int b    = blockIdx.x;
  const int t    = threadIdx.x;
  const int wave = t >> 6;
  const int lane = t & 63;

  const float* zb = z + (size_t)b * (CC * ZCH);
  const float* xb = x + (size_t)b * (CC * XCH);

  // Prefetch super-chunk 0
  stage_chunk(zbuf[0], zb, wave, lane);

  // Compute mapping: 288 active threads = g2 (0..31) x oyg (0..8)
  //   g2 = (cl 0..15) * 2 + (kyh 0..1); thread computes out rows 2*oyg, 2*oyg+1
  const int  g2     = t / 9;
  const int  oyg    = t - g2 * 9;
  const int  cl     = g2 >> 1;
  const int  kyh    = g2 & 1;            // 0: ky 0..2, 1: ky 3..5
  const bool active = (t < 288);
  const bool two    = (oyg < 8);         // oyg==8 handles only oy=16

  float acc0[HO], acc1[HO];
#pragma unroll
  for (int i = 0; i < HO; ++i) { acc0[i] = 0.0f; acc1[i] = 0.0f; }

  for (int k = 0; k < NCHUNK; ++k) {
    const int buf = k & 1;
    __syncthreads();   // chunk k's DMA complete; buf^1 reads (iter k-1) done

    // Prefetch next super-chunk; in flight across this iteration's compute.
    if (k + 1 < NCHUNK)
      stage_chunk(zbuf[buf ^ 1], zb + (size_t)(k + 1) * ZCHUNK, wave, lane);

    if (active) {
      // x taps for this (channel, ky-half): 18 floats from global (L1-hot).
      const float* xs = xb + ((size_t)(k * CHUNK_C + cl)) * XCH + kyh * 18;
      float xv[18];
#pragma unroll
      for (int j = 0; j < 9; ++j)
        ((float2*)xv)[j] = ((const float2*)xs)[j];

      const float* zc = &zbuf[buf][cl * ZCH];
      const int base_row = 2 * oyg + 3 * kyh;

#pragma unroll
      for (int ri = 0; ri < 4; ++ri) {
        // row base_row+ri feeds: p=0 (ky2=ri, ri<=2) and p=1 (ky2=ri-1, ri>=1)
        // (oyg==8, ri==3) would read row 22 (OOB) and only feeds p=1: skip.
        if (ri < 3 || two) {
          const float* zr = zc + (base_row + ri) * KZZ;
          float zv[KZZ + 2];
#pragma unroll
          for (int i = 0; i < 11; ++i)
            ((float2*)zv)[i] = ((const float2*)zr)[i];   // 11 ds_read_b64
          if (ri <= 2) {
#pragma unroll
            for (int kx = 0; kx < KXX; ++kx) {
              const float xs0 = xv[ri * KXX + kx];
#pragma unroll
              for (int ox = 0; ox < HO; ++ox)
                acc0[ox] = fmaf(zv[ox + kx], xs0, acc0[ox]);
            }
          }
          if (ri >= 1 && two) {
#pragma unroll
            for (int kx = 0; kx < KXX; ++kx) {
              const float xs1 = xv[(ri - 1) * KXX + kx];
#pragma unroll
              for (int ox = 0; ox < HO; ++ox)
                acc1[ox] = fmaf(zv[ox + kx], xs1, acc1[ox]);
            }
          }
        }
      }
    }
  }

  // Reduction: 32 partials (g2) per output pixel. Reuse zbuf as scratch:
  // 32*289 = 9248 floats = 37 KB <= 61.9 KB.
  __syncthreads();
  float* red = &zbuf[0][0];
  if (active) {
    const int oy0 = 2 * oyg;
#pragma unroll
    for (int ox = 0; ox < HO; ++ox)
      red[g2 * OUTHW + oy0 * HO + ox] = acc0[ox];
    if (two) {
#pragma unroll
      for (int ox = 0; ox < HO; ++ox)
        red[g2 * OUTHW + (oy0 + 1) * HO + ox] = acc1[ox];
    }
  }
  __syncthreads();
  if (t < OUTHW) {
    float s = 0.0f;
#pragma unroll
    for (int gg = 0; gg < 32; ++gg) s += red[gg * OUTHW + t];
    out[(size_t)b * OUTHW + t] = s;   // coalesced direct store
  }
}

extern "C" void kernel_launch(void* const* d_in, const int* in_sizes, int n_in,
                              void* d_out, int out_size, void* d_ws, size_t ws_size,
                              hipStream_t stream) {
  const float* x = (const float*)d_in[0];   // [512,256,6,6]
  const float* z = (const float*)d_in[1];   // [512,256,22,22]
  float* out = (float*)d_out;               // [512,1,17,17]
  corr_kernel<<<BB, NT, 0, stream>>>(x, z, out);
}